// Round 10
// baseline (210.344 us; speedup 1.0000x reference)
//
#include <hip/hip_runtime.h>
#include <hip/hip_bf16.h>

#define NB_ 16      // batches
#define LA_ 1024
#define LB_ 1024
#define H_  512

typedef __attribute__((ext_vector_type(8))) short short8;   // 8 bf16 = 4 VGPRs
typedef __attribute__((ext_vector_type(4))) float f32x4;    // MFMA C/D

using bf16 = __hip_bfloat16;

__device__ __forceinline__ float bf2f(unsigned short u) {
    union { unsigned int i; float f; } c; c.i = ((unsigned)u) << 16; return c.f;
}
__device__ __forceinline__ unsigned short f2bf(float f) {
    bf16 h = __float2bfloat16(f);
    return *(unsigned short*)&h;
}

__device__ __forceinline__ void load_lds16(const void* g, void* l) {
    __builtin_amdgcn_global_load_lds(
        (const __attribute__((address_space(1))) void*)g,
        (__attribute__((address_space(3))) void*)l, 16, 0, 0);
}

// ---------------------------------------------------------------------------
// MFMA GEMM core, 256x256 tile, BK=64, 8 waves, double-buffered 128 KiB LDS.
// Wave grid 4M x 2N (per-wave 64x128): av read ONCE per tile, each bv once.
//
// R10 deep counted schedule: per tile, issue ALL 8 next-tile loads at tile
// start, then ONE s_waitcnt vmcnt(8) + barrier. Invariants:
//  - per-wave vmcnt(8) with 16 outstanding retires the 8 oldest = this
//    wave's stripes of the CURRENT tile (issued one full tile ago ->
//    ~4 phases of latency cover, vs ~2 in the old p1/p3-wait scheme);
//  - the barrier after the wait publishes ALL waves' stripes (each wave
//    stages w*1024 stripes of every slab);
//  - ring write-after-read: next tile's issue happens after this tile's
//    end barrier, so all reads of the buffer being overwritten were issued
//    before any new write data can land.
// 8 loads stay in flight through every tile (was 2-4).
// LDS tiles [256][64] bf16, 16B chunk slot XOR-swizzled by (row&7)
// (bank-conflict-free, measured 0 conflicts).
// ---------------------------------------------------------------------------
template<int DB, int MODE>   // MODE 0 = steady (stage next), 1 = last tile
__device__ __forceinline__ void gemm_tile_cnt(
    const unsigned short* __restrict__ gA, const unsigned short* __restrict__ gB,
    int lda, int ldb, size_t ko,
    unsigned short* lds, char* lA, char* lB,
    const int* aoff, const int* boff, f32x4 acc[4][8])
{
    const char* bA = (const char*)lds + DB * 32768;
    const char* bB = (const char*)lds + 65536 + DB * 32768;
    const int nxt = (DB ^ 1) * 32768;
    if (MODE == 0) {                             // stage next tile, all 8 up front
#pragma unroll
        for (int s = 0; s < 4; s++) {
            load_lds16(gA + ko + (size_t)(s * 64) * lda, lA + nxt + s * 8192);
            load_lds16(gB + ko + (size_t)(s * 64) * ldb, lB + nxt + s * 8192);
        }
        asm volatile("s_waitcnt vmcnt(8)" ::: "memory");
    } else {
        asm volatile("s_waitcnt vmcnt(0)" ::: "memory");
    }
    __builtin_amdgcn_s_barrier();                // publish current tile's slabs
    short8 av[4][2];
#pragma unroll
    for (int p = 0; p < 4; ++p) {
        if (p == 0) {                            // A-frags once per tile
#pragma unroll
            for (int f = 0; f < 4; f++)
#pragma unroll
                for (int kk = 0; kk < 2; kk++)
                    av[f][kk] = *(const short8*)(bA + (aoff[f] ^ (kk << 6)));
        }
        short8 bv[2][2];
#pragma unroll
        for (int f = 0; f < 2; f++)
#pragma unroll
            for (int kk = 0; kk < 2; kk++)
                bv[f][kk] = *(const short8*)(bB + (boff[p * 2 + f] ^ (kk << 6)));
        __builtin_amdgcn_s_barrier();
        __builtin_amdgcn_s_setprio(1);
#pragma unroll
        for (int kk = 0; kk < 2; kk++)
#pragma unroll
            for (int f = 0; f < 2; f++)
#pragma unroll
                for (int m = 0; m < 4; m++)
                    acc[m][p * 2 + f] =
                        __builtin_amdgcn_mfma_f32_16x16x32_bf16(
                            av[m][kk], bv[f][kk], acc[m][p * 2 + f], 0, 0, 0);
        __builtin_amdgcn_s_setprio(0);
        __builtin_amdgcn_s_barrier();            // p<3: phase trail; p==3: tile end
    }
}

__device__ __forceinline__ void gemm_core256(
    const unsigned short* __restrict__ A, const unsigned short* __restrict__ B,
    int lda, int ldb, int K,
    unsigned short* lds, f32x4 acc[4][8])
{
    const int t = threadIdx.x;
    const int w = t >> 6, lane = t & 63;
    const int wr = w >> 1, wc = w & 1;          // wave grid 4 (M) x 2 (N)
    const int lm = lane & 15, q = lane >> 4;

    // fragment LDS byte offsets for kk=0; kk=1 is addr ^ 64 (chunk bit2 flip)
    int aoff[4], boff[8];
#pragma unroll
    for (int f = 0; f < 4; f++) {
        const int ra = wr * 64 + f * 16 + lm;
        aoff[f] = ra * 128 + ((q ^ (ra & 7)) << 4);
    }
#pragma unroll
    for (int f = 0; f < 8; f++) {
        const int rb = wc * 128 + f * 16 + lm;
        boff[f] = rb * 128 + ((q ^ (rb & 7)) << 4);
    }

    // staging addresses: load s covers rows [s*64,(s+1)*64); per wave 8 rows
    // x 128 B linear; source chunk pre-swizzled so LDS slot c holds global
    // chunk c ^ (row&7); row&7 == lane>>3 here.
    const int rstep = w * 8 + (lane >> 3);
    const int sc = (lane & 7) ^ (lane >> 3);
    const unsigned short* gA = A + (size_t)rstep * lda + sc * 8;
    const unsigned short* gB = B + (size_t)rstep * ldb + sc * 8;
    char* lA = (char*)lds + w * 1024;            // A buffers: bytes [0,65536)
    char* lB = (char*)lds + 65536 + w * 1024;    // B buffers: bytes [65536,131072)
    const int NT = K >> 6;

    // prologue: stage tile 0 into buffer 0 (waited inside tile 0's body)
#pragma unroll
    for (int s = 0; s < 4; s++) {
        load_lds16(gA + (size_t)(s * 64) * lda, lA + s * 8192);
        load_lds16(gB + (size_t)(s * 64) * ldb, lB + s * 8192);
    }
    int kt = 0;
    for (; kt + 2 < NT; kt += 2) {
        gemm_tile_cnt<0, 0>(gA, gB, lda, ldb, (size_t)(kt + 1) * 64,
                            lds, lA, lB, aoff, boff, acc);
        gemm_tile_cnt<1, 0>(gA, gB, lda, ldb, (size_t)(kt + 2) * 64,
                            lds, lA, lB, aoff, boff, acc);
    }
    gemm_tile_cnt<0, 0>(gA, gB, lda, ldb, (size_t)(NT - 1) * 64,
                        lds, lA, lB, aoff, boff, acc);
    gemm_tile_cnt<1, 1>(gA, gB, lda, ldb, 0, lds, lA, lB, aoff, boff, acc);
    __syncthreads();   // retire all LDS reads before callers reuse LDS
}

// ---------------------------------------------------------------------------
// GEMM1: S = a.b^T * temp; E = mask ? exp(S) : 0. Both E and ET written via
// LDS-transpose coalesced 512B-row stores (R9: direct scattered ET stores
// cost ~20-35 MB write amplification). ET-pass swizzle key jl&15 (R10: the
// old (jl>>1)&15 key had 8 distinct values over 16 rows -> 262K bank
// conflicts; full 4-bit key spreads 16 rows over 16 slots, <=2-way).
// Plus atomic l_row / l_col partials.
// Grid: 256 blocks, g = qq*16 + batch -> XCD batch%8 (panel L2 locality).
// ---------------------------------------------------------------------------
__global__ __launch_bounds__(512, 2) void k_gemm_attn(
    const unsigned short* __restrict__ a_bf, const unsigned short* __restrict__ b_bf,
    const int* __restrict__ mask_a, const int* __restrict__ mask_b,
    const float* __restrict__ temp_p,
    unsigned short* __restrict__ E, unsigned short* __restrict__ ET,
    float* __restrict__ l_row, float* __restrict__ l_col)
{
    __shared__ unsigned short lds[65536];        // 128 KiB: staging, E tile, ET tile

    const int g = blockIdx.x;
    const int batch = g & 15;
    const int qq = g >> 4;                       // 0..15
    const int i0 = (qq >> 2) * 256, j0 = (qq & 3) * 256;

    const unsigned short* A = a_bf + (size_t)batch * LA_ * H_ + (size_t)i0 * H_;
    const unsigned short* B = b_bf + (size_t)batch * LB_ * H_ + (size_t)j0 * H_;
    f32x4 acc[4][8];
#pragma unroll
    for (int x = 0; x < 4; x++)
#pragma unroll
        for (int y = 0; y < 8; y++) acc[x][y] = 0;

    gemm_core256(A, B, H_, H_, H_, lds, acc);

    const float temp = temp_p[0];
    const int t = threadIdx.x, w = t >> 6, lane = t & 63;
    const int wr = w >> 1, wc = w & 1, lm = lane & 15, q = lane >> 4;
    const int* map = mask_a + batch * LA_;
    const int* mbp = mask_b + batch * LB_;
    unsigned short* Ep  = E  + (size_t)batch * LA_ * LB_;
    unsigned short* ETp = ET + (size_t)batch * LB_ * LA_;
    float* lrp = l_row + batch * LA_;
    float* lcp = l_col + batch * LB_;

    int mb8[8];
#pragma unroll
    for (int fn = 0; fn < 8; fn++) mb8[fn] = mbp[j0 + wc * 128 + fn * 16 + lm];

    // transform acc -> e in place; write E tile into (now free) LDS with
    // chunk swizzle keyed on (il>>1)&15 (write conflict-free, row-read
    // bijective).
#pragma unroll
    for (int fm = 0; fm < 4; fm++) {
        const int ilb = wr * 64 + fm * 16 + q * 4;
        int ma[4];
#pragma unroll
        for (int r = 0; r < 4; r++) ma[r] = map[i0 + ilb + r];
#pragma unroll
        for (int fn = 0; fn < 8; fn++) {
            const int jl = wc * 128 + fn * 16 + lm;
#pragma unroll
            for (int r = 0; r < 4; r++) {
                const float e = (ma[r] && mb8[fn]) ? __expf(acc[fm][fn][r] * temp) : 0.0f;
                acc[fm][fn][r] = e;
                const int il = ilb + r;
                lds[il * 256 + ((((jl >> 3) ^ ((il >> 1) & 15)) << 3) | (jl & 7))] = f2bf(e);
            }
        }
    }

    // l_row partials: sum over this block's 256 j's (wave holds 128 of them;
    // two waves (wc=0,1) atomically combine)
#pragma unroll
    for (int fm = 0; fm < 4; fm++)
#pragma unroll
        for (int r = 0; r < 4; r++) {
            float s = 0.0f;
#pragma unroll
            for (int fn = 0; fn < 8; fn++) s += acc[fm][fn][r];
            s += __shfl_xor(s, 1, 16); s += __shfl_xor(s, 2, 16);
            s += __shfl_xor(s, 4, 16); s += __shfl_xor(s, 8, 16);
            if (lm == 0) atomicAdd(&lrp[i0 + wr * 64 + fm * 16 + q * 4 + r], s);
        }
    // l_col partials: sum over this block's 256 i's (wave holds 64; four
    // waves (wr) combine)
#pragma unroll
    for (int fn = 0; fn < 8; fn++) {
        float s = 0.0f;
#pragma unroll
        for (int fm = 0; fm < 4; fm++)
#pragma unroll
            for (int r = 0; r < 4; r++) s += acc[fm][fn][r];
        s += __shfl_xor(s, 16, 64); s += __shfl_xor(s, 32, 64);
        if (lane < 16) atomicAdd(&lcp[j0 + wc * 128 + fn * 16 + lm], s);
    }

    // packed E: coalesced 512B-row stores from the swizzled LDS tile
    __syncthreads();
#pragma unroll
    for (int rep = 0; rep < 16; rep++) {
        const int il = (t >> 5) + rep * 16;
        const int c = t & 31;
        const int phys = c ^ ((il >> 1) & 15);
        short8 v = *(const short8*)(lds + il * 256 + phys * 8);
        *(short8*)(Ep + (size_t)(i0 + il) * LB_ + j0 + c * 8) = v;
    }

    // ET tile: overwrite LDS with the transposed layout (rows = jl, 256
    // ushorts of il), chunk swizzle keyed on jl&15, then stream ET as
    // coalesced 512B rows.
    __syncthreads();
#pragma unroll
    for (int fm = 0; fm < 4; fm++) {
        const int ilb = wr * 64 + fm * 16 + q * 4;
        const int chunk = ilb >> 3, sub = ilb & 7;
#pragma unroll
        for (int fn = 0; fn < 8; fn++) {
            const int jl = wc * 128 + fn * 16 + lm;
            ushort4 pk;
            unsigned short* pp = (unsigned short*)&pk;
#pragma unroll
            for (int r = 0; r < 4; r++) pp[r] = f2bf(acc[fm][fn][r]);
            *(ushort4*)(lds + jl * 256 + (((chunk ^ (jl & 15)) << 3) | sub)) = pk;
        }
    }
    __syncthreads();
#pragma unroll
    for (int rep = 0; rep < 16; rep++) {
        const int jl = (t >> 5) + rep * 16;
        const int c = t & 31;
        const int phys = c ^ (jl & 15);
        short8 v = *(const short8*)(lds + jl * 256 + phys * 8);
        *(short8*)(ETp + (size_t)(j0 + jl) * LA_ + i0 + c * 8) = v;
    }
}

// ---------------------------------------------------------------------------
// GEMM2+3 merged: zc<16 -> feature_a (E . bT^T), zc>=16 -> feature_b (ET.aT^T)
// Grid: 256 blocks, g = qq*32 + zc -> XCD zc%8 (A-tile/B-panel L2 sharing).
// ---------------------------------------------------------------------------
__global__ __launch_bounds__(512, 2) void k_gemm_feat(
    const unsigned short* __restrict__ E, const unsigned short* __restrict__ ET,
    const unsigned short* __restrict__ aT, const unsigned short* __restrict__ bT,
    const int* __restrict__ mask_a, const int* __restrict__ mask_b,
    const int* __restrict__ nA, const int* __restrict__ nB,
    const float* __restrict__ l_row, const float* __restrict__ l_col,
    const float* __restrict__ mean_a, const float* __restrict__ mean_b,
    float* __restrict__ out)
{
    __shared__ unsigned short lds[65536];

    const int g = blockIdx.x;
    const int zc = g & 31;
    const int qq = g >> 5;                       // 0..7
    const int n0 = (qq & 1) * 256, m0 = (qq >> 1) * 256;

    const int batch = zc & 15;
    const bool isA = zc < 16;
    const unsigned short* Amat = (isA ? E : ET) + (size_t)batch * 1024 * 1024;
    const unsigned short* Bm   = (isA ? bT : aT) + (size_t)batch * H_ * 1024;
    const int* mp   = (isA ? mask_a : mask_b) + batch * 1024;
    const int nn    = (isA ? nB : nA)[batch];
    const float* sp = (isA ? l_row : l_col) + batch * 1024;
    const float* mv = (isA ? mean_b : mean_a) + batch * H_;
    float* op = out + (isA ? (size_t)0 : (size_t)NB_ * LA_ * H_) + (size_t)batch * 1024 * H_;

    f32x4 acc[4][8];
#pragma unroll
    for (int x = 0; x < 4; x++)
#pragma unroll
        for (int y = 0; y < 8; y++) acc[x][y] = 0;

    gemm_core256(Amat + (size_t)m0 * 1024, Bm + (size_t)n0 * 1024,
                 1024, 1024, 1024, lds, acc);

    const int t = threadIdx.x, w = t >> 6, lane = t & 63;
    const int wr = w >> 1, wc = w & 1, lm = lane & 15, q = lane >> 4;

    float mval[8];
#pragma unroll
    for (int fn = 0; fn < 8; fn++) mval[fn] = mv[n0 + wc * 128 + fn * 16 + lm];

#pragma unroll
    for (int fm = 0; fm < 4; fm++) {
        const int ib = m0 + wr * 64 + fm * 16 + q * 4;
#pragma unroll
        for (int r = 0; r < 4; r++) {
            const int i = ib + r;
            const bool valid = (mp[i] != 0) && (nn > 0);
            const float inv = valid ? 1.0f / sp[i] : 0.0f;
#pragma unroll
            for (int fn = 0; fn < 8; fn++) {
                const int d = n0 + wc * 128 + fn * 16 + lm;
                op[(size_t)i * H_ + d] = valid ? acc[fm][fn][r] * inv : mval[fn];
            }
        }
    }
}

// ---------------------------------------------------------------------------
// prep: block-owned column panels -> NO atomics.  [R6 version]
// Blocks 0..255: (sel, batch, 64-d strip); loop over all 1024 tokens:
//   fp32 -> bf16 row-major + LDS-transposed bf16, column sums in registers,
//   shfl + small-LDS reduce -> direct mean store (single writer).
// Blocks 256..287: zero l_row/l_col (128 KB) + per-batch mask counts.
// ---------------------------------------------------------------------------
__global__ __launch_bounds__(256) void k_prep(
    const float* __restrict__ a, const float* __restrict__ b,
    unsigned short* __restrict__ aN, unsigned short* __restrict__ bN,
    unsigned short* __restrict__ aT, unsigned short* __restrict__ bT,
    float* __restrict__ mean_a, float* __restrict__ mean_b,
    const int* __restrict__ mask_a, const int* __restrict__ mask_b,
    int* __restrict__ nA, int* __restrict__ nB,
    float* __restrict__ zero_base)
{
    const int g = blockIdx.x, t = threadIdx.x;
    if (g >= 256) {
        const int s = g - 256;                   // 0..31
        *(float4*)(zero_base + ((size_t)s * 256 + t) * 4) = make_float4(0, 0, 0, 0);
        const int batch = s & 15, which = s >> 4;
        const int* m = (which ? mask_b : mask_a) + batch * 1024;
        int cnt = m[t] + m[t + 256] + m[t + 512] + m[t + 768];
        __shared__ int red[256];
        red[t] = cnt;
        __syncthreads();
        for (int off = 128; off; off >>= 1) {
            if (t < off) red[t] += red[t + off];
            __syncthreads();
        }
        if (t == 0) (which ? nB : nA)[batch] = red[0];
        return;
    }
    const int dstrip = g & 7, batch = (g >> 3) & 15, sel = g >> 7;
    const float* src = (sel ? b : a) + (size_t)batch * 1024 * H_;
    unsigned short* np = (sel ? bN : aN) + (size_t)batch * 1024 * H_;
    unsigned short* tp = (sel ? bT : aT) + (size_t)batch * H_ * 1024;
    float* mdst = (sel ? mean_b : mean_a) + batch * H_;
    const int d0 = dstrip * 64;

    __shared__ unsigned short lds[64][68];
    __shared__ float cs[4][64];
    const int c4 = (t & 15) * 4;
    float colsum[4] = {0.f, 0.f, 0.f, 0.f};
    for (int i0 = 0; i0 < 1024; i0 += 64) {
#pragma unroll
        for (int it = 0; it < 4; it++) {
            const int r = (t >> 4) + it * 16;
            float4 v = *(const float4*)(src + (size_t)(i0 + r) * H_ + d0 + c4);
            colsum[0] += v.x; colsum[1] += v.y; colsum[2] += v.z; colsum[3] += v.w;
            ushort4 u = make_ushort4(f2bf(v.x), f2bf(v.y), f2bf(v.z), f2bf(v.w));
            *(ushort4*)(np + (size_t)(i0 + r) * H_ + d0 + c4) = u;
            *(ushort4*)&lds[r][c4] = u;
        }
        __syncthreads();
#pragma unroll
        for (int it = 0; it < 4; it++) {
            const int dd = (t >> 4) + it * 16;
            const int i4 = (t & 15) * 4;
            ushort4 u = make_ushort4(lds[i4][dd], lds[i4 + 1][dd],
                                     lds[i4 + 2][dd], lds[i4 + 3][dd]);
            *(ushort4*)(tp + (size_t)(d0 + dd) * 1024 + i0 + i4) = u;
        }
        __syncthreads();
    }
    // columns are shared by threads t, t^16, t^32 (within wave) x 4 waves
#pragma unroll
    for (int j = 0; j < 4; j++) {
        colsum[j] += __shfl_xor(colsum[j], 16, 64);
        colsum[j] += __shfl_xor(colsum[j], 32, 64);
    }
    const int w = t >> 6, lane = t & 63;
    if (lane < 16) {
#pragma unroll
        for (int j = 0; j < 4; j++) cs[w][c4 + j] = colsum[j];
    }
    __syncthreads();
    if (t < 64) mdst[d0 + t] = (cs[0][t] + cs[1][t] + cs[2][t] + cs[3][t]) * (1.0f / 1024.0f);
}

// ---------------------------------------------------------------------------
extern "C" void kernel_launch(void* const* d_in, const int* in_sizes, int n_in,
                              void* d_out, int out_size, void* d_ws, size_t ws_size,
                              hipStream_t stream)
{
    const float* a      = (const float*)d_in[0];
    const float* b      = (const float*)d_in[1];
    const int*   mask_a = (const int*)d_in[2];
    const int*   mask_b = (const int*)d_in[3];
    const float* temp   = (const float*)d_in[4];
    float* out = (float*)d_out;

    // workspace layout (~128.2 MiB)
    char* ws = (char*)d_ws;
    size_t off = 0;
    unsigned short* E    = (unsigned short*)(ws + off); off += (size_t)NB_ * LA_ * LB_ * 2;  // 32 MiB
    unsigned short* ET   = (unsigned short*)(ws + off); off += (size_t)NB_ * LB_ * LA_ * 2;  // 32 MiB
    unsigned short* a_bf = (unsigned short*)(ws + off); off += (size_t)NB_ * LA_ * H_ * 2;   // 16 MiB
    unsigned short* b_bf = (unsigned short*)(ws + off); off += (size_t)NB_ * LB_ * H_ * 2;   // 16 MiB
    unsigned short* aT   = (unsigned short*)(ws + off); off += (size_t)NB_ * H_ * LA_ * 2;   // 16 MiB
    unsigned short* bT   = (unsigned short*)(ws + off); off += (size_t)NB_ * H_ * LB_ * 2;   // 16 MiB
    float* l_row  = (float*)(ws + off); off += (size_t)NB_ * LA_ * 4;   // zeroed region start
    float* l_col  = (float*)(ws + off); off += (size_t)NB_ * LB_ * 4;
    float* mean_a = (float*)(ws + off); off += (size_t)NB_ * H_ * 4;
    float* mean_b = (float*)(ws + off); off += (size_t)NB_ * H_ * 4;
    int*   nA     = (int*)(ws + off); off += 64;
    int*   nB     = (int*)(ws + off); off += 64;

    // prep (also zeroes l_row/l_col and computes mask counts)
    k_prep<<<dim3(288), 256, 0, stream>>>(
        a, b, a_bf, b_bf, aT, bT, mean_a, mean_b,
        mask_a, mask_b, nA, nB, l_row);

    k_gemm_attn<<<dim3(256), 512, 0, stream>>>(
        a_bf, b_bf, mask_a, mask_b, temp, E, ET, l_row, l_col);

    k_gemm_feat<<<dim3(256), 512, 0, stream>>>(
        E, ET, aT, bT, mask_a, mask_b, nA, nB, l_row, l_col, mean_a, mean_b, out);
}

// Round 11
// 203.893 us; speedup vs baseline: 1.0316x; 1.0316x over previous
//
#include <hip/hip_runtime.h>
#include <hip/hip_bf16.h>

#define NB_ 16      // batches
#define LA_ 1024
#define LB_ 1024
#define H_  512

typedef __attribute__((ext_vector_type(8))) short short8;   // 8 bf16 = 4 VGPRs
typedef __attribute__((ext_vector_type(4))) float f32x4;    // MFMA C/D

using bf16 = __hip_bfloat16;

__device__ __forceinline__ float bf2f(unsigned short u) {
    union { unsigned int i; float f; } c; c.i = ((unsigned)u) << 16; return c.f;
}
__device__ __forceinline__ unsigned short f2bf(float f) {
    bf16 h = __float2bfloat16(f);
    return *(unsigned short*)&h;
}

__device__ __forceinline__ void load_lds16(const void* g, void* l) {
    __builtin_amdgcn_global_load_lds(
        (const __attribute__((address_space(1))) void*)g,
        (__attribute__((address_space(3))) void*)l, 16, 0, 0);
}

// ---------------------------------------------------------------------------
// MFMA GEMM core, 256x256 tile, BK=64, 8 waves, double-buffered 128 KiB LDS.
// Wave grid 4M x 2N (per-wave 64x128): av read ONCE per tile, each bv once.
// R9 counted schedule (best verified; R10's deeper tile-start wait REGRESSED
// -25%: the wait sat before any compute, un-overlapped — wait POSITION after
// MFMA clusters beats wait depth):
//   stage 2 loads/phase in order A0,A1|A2,A3|B0,B2|B1,B3; s_waitcnt
//   vmcnt(4)@p1 / vmcnt(2)@p3 placed AFTER the MFMA cluster; never drain
//   in-loop. Invariant: entering a tile only B1,B3 of the CURRENT buffer
//   are in flight; first read at p2, retired by p1's vmcnt(4).
// LDS tiles [256][64] bf16, 16B chunk slot XOR-swizzled by (row&7)
// (bank-conflict-free, measured 0 conflicts).
// ---------------------------------------------------------------------------
template<int DB, int MODE>   // MODE 0 = steady (stage next), 1 = last tile
__device__ __forceinline__ void gemm_tile_cnt(
    const unsigned short* __restrict__ gA, const unsigned short* __restrict__ gB,
    int lda, int ldb, size_t ko,
    unsigned short* lds, char* lA, char* lB,
    const int* aoff, const int* boff, f32x4 acc[4][8])
{
    const char* bA = (const char*)lds + DB * 32768;
    const char* bB = (const char*)lds + 65536 + DB * 32768;
    const int nxt = (DB ^ 1) * 32768;
    short8 av[4][2];
#pragma unroll
    for (int p = 0; p < 4; ++p) {
        if (p == 0) {                            // A-frags once per tile
#pragma unroll
            for (int f = 0; f < 4; f++)
#pragma unroll
                for (int kk = 0; kk < 2; kk++)
                    av[f][kk] = *(const short8*)(bA + (aoff[f] ^ (kk << 6)));
        }
        short8 bv[2][2];
#pragma unroll
        for (int f = 0; f < 2; f++)
#pragma unroll
            for (int kk = 0; kk < 2; kk++)
                bv[f][kk] = *(const short8*)(bB + (boff[p * 2 + f] ^ (kk << 6)));
        if (MODE == 0) {                         // stage next tile, 2 per phase
            if (p == 0) {
                load_lds16(gA + ko,                       lA + nxt);
                load_lds16(gA + ko + (size_t)64 * lda,    lA + nxt + 8192);
            } else if (p == 1) {
                load_lds16(gA + ko + (size_t)128 * lda,   lA + nxt + 16384);
                load_lds16(gA + ko + (size_t)192 * lda,   lA + nxt + 24576);
            } else if (p == 2) {
                load_lds16(gB + ko,                       lB + nxt);
                load_lds16(gB + ko + (size_t)128 * ldb,   lB + nxt + 16384);
            } else {
                load_lds16(gB + ko + (size_t)64 * ldb,    lB + nxt + 8192);
                load_lds16(gB + ko + (size_t)192 * ldb,   lB + nxt + 24576);
            }
        }
        __builtin_amdgcn_s_barrier();
        __builtin_amdgcn_s_setprio(1);
#pragma unroll
        for (int kk = 0; kk < 2; kk++)
#pragma unroll
            for (int f = 0; f < 2; f++)
#pragma unroll
                for (int m = 0; m < 4; m++)
                    acc[m][p * 2 + f] =
                        __builtin_amdgcn_mfma_f32_16x16x32_bf16(
                            av[m][kk], bv[f][kk], acc[m][p * 2 + f], 0, 0, 0);
        __builtin_amdgcn_s_setprio(0);
        if (p == 1) {
            if (MODE == 0) asm volatile("s_waitcnt vmcnt(4)" ::: "memory");
            else           asm volatile("s_waitcnt vmcnt(0)" ::: "memory");
        }
        if (p == 3 && MODE == 0) asm volatile("s_waitcnt vmcnt(2)" ::: "memory");
        if (p < 3 || MODE == 0) __builtin_amdgcn_s_barrier();
    }
}

__device__ __forceinline__ void gemm_core256(
    const unsigned short* __restrict__ A, const unsigned short* __restrict__ B,
    int lda, int ldb, int K,
    unsigned short* lds, f32x4 acc[4][8])
{
    const int t = threadIdx.x;
    const int w = t >> 6, lane = t & 63;
    const int wr = w >> 1, wc = w & 1;          // wave grid 4 (M) x 2 (N)
    const int lm = lane & 15, q = lane >> 4;

    // fragment LDS byte offsets for kk=0; kk=1 is addr ^ 64 (chunk bit2 flip)
    int aoff[4], boff[8];
#pragma unroll
    for (int f = 0; f < 4; f++) {
        const int ra = wr * 64 + f * 16 + lm;
        aoff[f] = ra * 128 + ((q ^ (ra & 7)) << 4);
    }
#pragma unroll
    for (int f = 0; f < 8; f++) {
        const int rb = wc * 128 + f * 16 + lm;
        boff[f] = rb * 128 + ((q ^ (rb & 7)) << 4);
    }

    // staging addresses: load s covers rows [s*64,(s+1)*64); per wave 8 rows
    // x 128 B linear; source chunk pre-swizzled so LDS slot c holds global
    // chunk c ^ (row&7); row&7 == lane>>3 here.
    const int rstep = w * 8 + (lane >> 3);
    const int sc = (lane & 7) ^ (lane >> 3);
    const unsigned short* gA = A + (size_t)rstep * lda + sc * 8;
    const unsigned short* gB = B + (size_t)rstep * ldb + sc * 8;
    char* lA = (char*)lds + w * 1024;            // A buffers: bytes [0,65536)
    char* lB = (char*)lds + 65536 + w * 1024;    // B buffers: bytes [65536,131072)
    const int NT = K >> 6;

    // prologue order A0,A1,A2,A3,B0,B2,B1,B3 matches counted waits:
    // vmcnt(2) leaves B1,B3 in flight (first read at p2, covered by
    // p1's vmcnt(4))
    load_lds16(gA,                       lA);
    load_lds16(gA + (size_t)64 * lda,    lA + 8192);
    load_lds16(gA + (size_t)128 * lda,   lA + 16384);
    load_lds16(gA + (size_t)192 * lda,   lA + 24576);
    load_lds16(gB,                       lB);
    load_lds16(gB + (size_t)128 * ldb,   lB + 16384);
    load_lds16(gB + (size_t)64 * ldb,    lB + 8192);
    load_lds16(gB + (size_t)192 * ldb,   lB + 24576);
    asm volatile("s_waitcnt vmcnt(2)" ::: "memory");
    __builtin_amdgcn_s_barrier();
    int kt = 0;
    for (; kt + 2 < NT; kt += 2) {
        gemm_tile_cnt<0, 0>(gA, gB, lda, ldb, (size_t)(kt + 1) * 64,
                            lds, lA, lB, aoff, boff, acc);
        gemm_tile_cnt<1, 0>(gA, gB, lda, ldb, (size_t)(kt + 2) * 64,
                            lds, lA, lB, aoff, boff, acc);
    }
    gemm_tile_cnt<0, 0>(gA, gB, lda, ldb, (size_t)(NT - 1) * 64,
                        lds, lA, lB, aoff, boff, acc);
    gemm_tile_cnt<1, 1>(gA, gB, lda, ldb, 0, lds, lA, lB, aoff, boff, acc);
    __syncthreads();   // retire all LDS reads before callers reuse LDS
}

// ---------------------------------------------------------------------------
// GEMM1: S = a.b^T * temp; E = mask ? exp(S) : 0. Both E and ET written via
// LDS-transpose coalesced 512B-row stores. ET-pass swizzle key jl&15 (kept
// from R10: R9's (jl>>1)&15 key had only 8 distinct values over the 16 rows
// a lane-group touches -> 262K bank conflicts; full 4-bit key -> key=lm per
// lane-group, 16 distinct chunk slots, ~2-way = free).
// Plus atomic l_row / l_col partials.
// Grid: 256 blocks, g = qq*16 + batch -> XCD batch%8 (panel L2 locality).
// ---------------------------------------------------------------------------
__global__ __launch_bounds__(512, 2) void k_gemm_attn(
    const unsigned short* __restrict__ a_bf, const unsigned short* __restrict__ b_bf,
    const int* __restrict__ mask_a, const int* __restrict__ mask_b,
    const float* __restrict__ temp_p,
    unsigned short* __restrict__ E, unsigned short* __restrict__ ET,
    float* __restrict__ l_row, float* __restrict__ l_col)
{
    __shared__ unsigned short lds[65536];        // 128 KiB: staging, E tile, ET tile

    const int g = blockIdx.x;
    const int batch = g & 15;
    const int qq = g >> 4;                       // 0..15
    const int i0 = (qq >> 2) * 256, j0 = (qq & 3) * 256;

    const unsigned short* A = a_bf + (size_t)batch * LA_ * H_ + (size_t)i0 * H_;
    const unsigned short* B = b_bf + (size_t)batch * LB_ * H_ + (size_t)j0 * H_;
    f32x4 acc[4][8];
#pragma unroll
    for (int x = 0; x < 4; x++)
#pragma unroll
        for (int y = 0; y < 8; y++) acc[x][y] = 0;

    gemm_core256(A, B, H_, H_, H_, lds, acc);

    const float temp = temp_p[0];
    const int t = threadIdx.x, w = t >> 6, lane = t & 63;
    const int wr = w >> 1, wc = w & 1, lm = lane & 15, q = lane >> 4;
    const int* map = mask_a + batch * LA_;
    const int* mbp = mask_b + batch * LB_;
    unsigned short* Ep  = E  + (size_t)batch * LA_ * LB_;
    unsigned short* ETp = ET + (size_t)batch * LB_ * LA_;
    float* lrp = l_row + batch * LA_;
    float* lcp = l_col + batch * LB_;

    int mb8[8];
#pragma unroll
    for (int fn = 0; fn < 8; fn++) mb8[fn] = mbp[j0 + wc * 128 + fn * 16 + lm];

    // transform acc -> e in place; write E tile into (now free) LDS with
    // chunk swizzle keyed on (il>>1)&15 (write conflict-free, row-read
    // bijective).
#pragma unroll
    for (int fm = 0; fm < 4; fm++) {
        const int ilb = wr * 64 + fm * 16 + q * 4;
        int ma[4];
#pragma unroll
        for (int r = 0; r < 4; r++) ma[r] = map[i0 + ilb + r];
#pragma unroll
        for (int fn = 0; fn < 8; fn++) {
            const int jl = wc * 128 + fn * 16 + lm;
#pragma unroll
            for (int r = 0; r < 4; r++) {
                const float e = (ma[r] && mb8[fn]) ? __expf(acc[fm][fn][r] * temp) : 0.0f;
                acc[fm][fn][r] = e;
                const int il = ilb + r;
                lds[il * 256 + ((((jl >> 3) ^ ((il >> 1) & 15)) << 3) | (jl & 7))] = f2bf(e);
            }
        }
    }

    // l_row partials: sum over this block's 256 j's (wave holds 128 of them;
    // two waves (wc=0,1) atomically combine)
#pragma unroll
    for (int fm = 0; fm < 4; fm++)
#pragma unroll
        for (int r = 0; r < 4; r++) {
            float s = 0.0f;
#pragma unroll
            for (int fn = 0; fn < 8; fn++) s += acc[fm][fn][r];
            s += __shfl_xor(s, 1, 16); s += __shfl_xor(s, 2, 16);
            s += __shfl_xor(s, 4, 16); s += __shfl_xor(s, 8, 16);
            if (lm == 0) atomicAdd(&lrp[i0 + wr * 64 + fm * 16 + q * 4 + r], s);
        }
    // l_col partials: sum over this block's 256 i's (wave holds 64; four
    // waves (wr) combine)
#pragma unroll
    for (int fn = 0; fn < 8; fn++) {
        float s = 0.0f;
#pragma unroll
        for (int fm = 0; fm < 4; fm++)
#pragma unroll
            for (int r = 0; r < 4; r++) s += acc[fm][fn][r];
        s += __shfl_xor(s, 16, 64); s += __shfl_xor(s, 32, 64);
        if (lane < 16) atomicAdd(&lcp[j0 + wc * 128 + fn * 16 + lm], s);
    }

    // packed E: coalesced 512B-row stores from the swizzled LDS tile
    __syncthreads();
#pragma unroll
    for (int rep = 0; rep < 16; rep++) {
        const int il = (t >> 5) + rep * 16;
        const int c = t & 31;
        const int phys = c ^ ((il >> 1) & 15);
        short8 v = *(const short8*)(lds + il * 256 + phys * 8);
        *(short8*)(Ep + (size_t)(i0 + il) * LB_ + j0 + c * 8) = v;
    }

    // ET tile: overwrite LDS with the transposed layout (rows = jl, 256
    // ushorts of il), chunk swizzle keyed on jl&15, then stream ET as
    // coalesced 512B rows.
    __syncthreads();
#pragma unroll
    for (int fm = 0; fm < 4; fm++) {
        const int ilb = wr * 64 + fm * 16 + q * 4;
        const int chunk = ilb >> 3, sub = ilb & 7;
#pragma unroll
        for (int fn = 0; fn < 8; fn++) {
            const int jl = wc * 128 + fn * 16 + lm;
            ushort4 pk;
            unsigned short* pp = (unsigned short*)&pk;
#pragma unroll
            for (int r = 0; r < 4; r++) pp[r] = f2bf(acc[fm][fn][r]);
            *(ushort4*)(lds + jl * 256 + (((chunk ^ (jl & 15)) << 3) | sub)) = pk;
        }
    }
    __syncthreads();
#pragma unroll
    for (int rep = 0; rep < 16; rep++) {
        const int jl = (t >> 5) + rep * 16;
        const int c = t & 31;
        const int phys = c ^ (jl & 15);
        short8 v = *(const short8*)(lds + jl * 256 + phys * 8);
        *(short8*)(ETp + (size_t)(j0 + jl) * LA_ + i0 + c * 8) = v;
    }
}

// ---------------------------------------------------------------------------
// GEMM2+3 merged: zc<16 -> feature_a (E . bT^T), zc>=16 -> feature_b (ET.aT^T)
// Grid: 256 blocks, g = qq*32 + zc -> XCD zc%8 (A-tile/B-panel L2 sharing).
// Means come as 2 token-half partials (prep split) -> mval sums 2 scalars.
// ---------------------------------------------------------------------------
__global__ __launch_bounds__(512, 2) void k_gemm_feat(
    const unsigned short* __restrict__ E, const unsigned short* __restrict__ ET,
    const unsigned short* __restrict__ aT, const unsigned short* __restrict__ bT,
    const int* __restrict__ mask_a, const int* __restrict__ mask_b,
    const int* __restrict__ nA, const int* __restrict__ nB,
    const float* __restrict__ l_row, const float* __restrict__ l_col,
    const float* __restrict__ mean_a_p, const float* __restrict__ mean_b_p,
    float* __restrict__ out)
{
    __shared__ unsigned short lds[65536];

    const int g = blockIdx.x;
    const int zc = g & 31;
    const int qq = g >> 5;                       // 0..7
    const int n0 = (qq & 1) * 256, m0 = (qq >> 1) * 256;

    const int batch = zc & 15;
    const bool isA = zc < 16;
    const unsigned short* Amat = (isA ? E : ET) + (size_t)batch * 1024 * 1024;
    const unsigned short* Bm   = (isA ? bT : aT) + (size_t)batch * H_ * 1024;
    const int* mp   = (isA ? mask_a : mask_b) + batch * 1024;
    const int nn    = (isA ? nB : nA)[batch];
    const float* sp = (isA ? l_row : l_col) + batch * 1024;
    const float* mvp = (isA ? mean_b_p : mean_a_p) + (size_t)batch * 1024;
    float* op = out + (isA ? (size_t)0 : (size_t)NB_ * LA_ * H_) + (size_t)batch * 1024 * H_;

    f32x4 acc[4][8];
#pragma unroll
    for (int x = 0; x < 4; x++)
#pragma unroll
        for (int y = 0; y < 8; y++) acc[x][y] = 0;

    gemm_core256(Amat + (size_t)m0 * 1024, Bm + (size_t)n0 * 1024,
                 1024, 1024, 1024, lds, acc);

    const int t = threadIdx.x, w = t >> 6, lane = t & 63;
    const int wr = w >> 1, wc = w & 1, lm = lane & 15, q = lane >> 4;

    float mval[8];
#pragma unroll
    for (int fn = 0; fn < 8; fn++) {
        const int d = n0 + wc * 128 + fn * 16 + lm;
        mval[fn] = mvp[d] + mvp[512 + d];
    }

#pragma unroll
    for (int fm = 0; fm < 4; fm++) {
        const int ib = m0 + wr * 64 + fm * 16 + q * 4;
#pragma unroll
        for (int r = 0; r < 4; r++) {
            const int i = ib + r;
            const bool valid = (mp[i] != 0) && (nn > 0);
            const float inv = valid ? 1.0f / sp[i] : 0.0f;
#pragma unroll
            for (int fn = 0; fn < 8; fn++) {
                const int d = n0 + wc * 128 + fn * 16 + lm;
                op[(size_t)i * H_ + d] = valid ? acc[fm][fn][r] * inv : mval[fn];
            }
        }
    }
}

// ---------------------------------------------------------------------------
// prep: R11 split — 512 blocks (2/CU, 8 waves/CU; was 256 blocks = 1.1/CU,
// no latency hiding on a memory-bound kernel). Block = (sel, batch,
// 512-token half, 64-d strip); loop 512 tokens:
//   fp32 -> bf16 row-major + LDS-transposed bf16, column sums in registers,
//   shfl + small-LDS reduce -> per-half mean partial (no atomics, no zero).
// Blocks 512..543: zero l_row/l_col (128 KB) + per-batch mask counts.
// ---------------------------------------------------------------------------
__global__ __launch_bounds__(256) void k_prep(
    const float* __restrict__ a, const float* __restrict__ b,
    unsigned short* __restrict__ aN, unsigned short* __restrict__ bN,
    unsigned short* __restrict__ aT, unsigned short* __restrict__ bT,
    float* __restrict__ mean_a_p, float* __restrict__ mean_b_p,
    const int* __restrict__ mask_a, const int* __restrict__ mask_b,
    int* __restrict__ nA, int* __restrict__ nB,
    float* __restrict__ zero_base)
{
    const int g = blockIdx.x, t = threadIdx.x;
    if (g >= 512) {
        const int s = g - 512;                   // 0..31
        *(float4*)(zero_base + ((size_t)s * 256 + t) * 4) = make_float4(0, 0, 0, 0);
        const int batch = s & 15, which = s >> 4;
        const int* m = (which ? mask_b : mask_a) + batch * 1024;
        int cnt = m[t] + m[t + 256] + m[t + 512] + m[t + 768];
        __shared__ int red[256];
        red[t] = cnt;
        __syncthreads();
        for (int off = 128; off; off >>= 1) {
            if (t < off) red[t] += red[t + off];
            __syncthreads();
        }
        if (t == 0) (which ? nB : nA)[batch] = red[0];
        return;
    }
    const int dstrip = g & 7, th = (g >> 3) & 1, batch = (g >> 4) & 15, sel = g >> 8;
    const float* src = (sel ? b : a) + (size_t)batch * 1024 * H_;
    unsigned short* np = (sel ? bN : aN) + (size_t)batch * 1024 * H_;
    unsigned short* tp = (sel ? bT : aT) + (size_t)batch * H_ * 1024;
    float* mdst = (sel ? mean_b_p : mean_a_p) + (size_t)batch * 1024 + th * 512;
    const int d0 = dstrip * 64;
    const int ibase = th * 512;

    __shared__ unsigned short lds[64][68];
    __shared__ float cs[4][64];
    const int c4 = (t & 15) * 4;
    float colsum[4] = {0.f, 0.f, 0.f, 0.f};
    for (int ii = 0; ii < 512; ii += 64) {
        const int i0 = ibase + ii;
#pragma unroll
        for (int it = 0; it < 4; it++) {
            const int r = (t >> 4) + it * 16;
            float4 v = *(const float4*)(src + (size_t)(i0 + r) * H_ + d0 + c4);
            colsum[0] += v.x; colsum[1] += v.y; colsum[2] += v.z; colsum[3] += v.w;
            ushort4 u = make_ushort4(f2bf(v.x), f2bf(v.y), f2bf(v.z), f2bf(v.w));
            *(ushort4*)(np + (size_t)(i0 + r) * H_ + d0 + c4) = u;
            *(ushort4*)&lds[r][c4] = u;
        }
        __syncthreads();
#pragma unroll
        for (int it = 0; it < 4; it++) {
            const int dd = (t >> 4) + it * 16;
            const int i4 = (t & 15) * 4;
            ushort4 u = make_ushort4(lds[i4][dd], lds[i4 + 1][dd],
                                     lds[i4 + 2][dd], lds[i4 + 3][dd]);
            *(ushort4*)(tp + (size_t)(d0 + dd) * 1024 + i0 + i4) = u;
        }
        __syncthreads();
    }
    // columns are shared by threads t, t^16, t^32 (within wave) x 4 waves
#pragma unroll
    for (int j = 0; j < 4; j++) {
        colsum[j] += __shfl_xor(colsum[j], 16, 64);
        colsum[j] += __shfl_xor(colsum[j], 32, 64);
    }
    const int w = t >> 6, lane = t & 63;
    if (lane < 16) {
#pragma unroll
        for (int j = 0; j < 4; j++) cs[w][c4 + j] = colsum[j];
    }
    __syncthreads();
    if (t < 64) mdst[d0 + t] = (cs[0][t] + cs[1][t] + cs[2][t] + cs[3][t]) * (1.0f / 1024.0f);
}

// ---------------------------------------------------------------------------
extern "C" void kernel_launch(void* const* d_in, const int* in_sizes, int n_in,
                              void* d_out, int out_size, void* d_ws, size_t ws_size,
                              hipStream_t stream)
{
    const float* a      = (const float*)d_in[0];
    const float* b      = (const float*)d_in[1];
    const int*   mask_a = (const int*)d_in[2];
    const int*   mask_b = (const int*)d_in[3];
    const float* temp   = (const float*)d_in[4];
    float* out = (float*)d_out;

    // workspace layout (~128.3 MiB)
    char* ws = (char*)d_ws;
    size_t off = 0;
    unsigned short* E    = (unsigned short*)(ws + off); off += (size_t)NB_ * LA_ * LB_ * 2;  // 32 MiB
    unsigned short* ET   = (unsigned short*)(ws + off); off += (size_t)NB_ * LB_ * LA_ * 2;  // 32 MiB
    unsigned short* a_bf = (unsigned short*)(ws + off); off += (size_t)NB_ * LA_ * H_ * 2;   // 16 MiB
    unsigned short* b_bf = (unsigned short*)(ws + off); off += (size_t)NB_ * LB_ * H_ * 2;   // 16 MiB
    unsigned short* aT   = (unsigned short*)(ws + off); off += (size_t)NB_ * H_ * LA_ * 2;   // 16 MiB
    unsigned short* bT   = (unsigned short*)(ws + off); off += (size_t)NB_ * H_ * LB_ * 2;   // 16 MiB
    float* l_row    = (float*)(ws + off); off += (size_t)NB_ * LA_ * 4;      // zeroed region start
    float* l_col    = (float*)(ws + off); off += (size_t)NB_ * LB_ * 4;
    float* mean_a_p = (float*)(ws + off); off += (size_t)NB_ * 2 * H_ * 4;   // 64 KiB (2 halves)
    float* mean_b_p = (float*)(ws + off); off += (size_t)NB_ * 2 * H_ * 4;   // 64 KiB
    int*   nA     = (int*)(ws + off); off += 64;
    int*   nB     = (int*)(ws + off); off += 64;

    // prep (also zeroes l_row/l_col and computes mask counts)
    k_prep<<<dim3(544), 256, 0, stream>>>(
        a, b, a_bf, b_bf, aT, bT, mean_a_p, mean_b_p,
        mask_a, mask_b, nA, nB, l_row);

    k_gemm_attn<<<dim3(256), 512, 0, stream>>>(
        a_bf, b_bf, mask_a, mask_b, temp, E, ET, l_row, l_col);

    k_gemm_feat<<<dim3(256), 512, 0, stream>>>(
        E, ET, aT, bT, mask_a, mask_b, nA, nB,
        l_row, l_col, mean_a_p, mean_b_p, out);
}

// Round 12
// 199.684 us; speedup vs baseline: 1.0534x; 1.0211x over previous
//
#include <hip/hip_runtime.h>
#include <hip/hip_bf16.h>

#define NB_ 16      // batches
#define LA_ 1024
#define LB_ 1024
#define H_  512

typedef __attribute__((ext_vector_type(8))) short short8;   // 8 bf16 = 4 VGPRs
typedef __attribute__((ext_vector_type(4))) float f32x4;    // MFMA C/D

using bf16 = __hip_bfloat16;

__device__ __forceinline__ float bf2f(unsigned short u) {
    union { unsigned int i; float f; } c; c.i = ((unsigned)u) << 16; return c.f;
}
__device__ __forceinline__ unsigned short f2bf(float f) {
    bf16 h = __float2bfloat16(f);
    return *(unsigned short*)&h;
}

__device__ __forceinline__ void load_lds16(const void* g, void* l) {
    __builtin_amdgcn_global_load_lds(
        (const __attribute__((address_space(1))) void*)g,
        (__attribute__((address_space(3))) void*)l, 16, 0, 0);
}

// ---------------------------------------------------------------------------
// MFMA GEMM core, 256x256 tile, BK=64, 8 waves, double-buffered 128 KiB LDS.
// Wave grid 4M x 2N (per-wave 64x128): av read ONCE per tile, each bv once.
// Counted schedule (best verified across R8-R11 bracketing: deeper
// tile-start wait -25% [R10], shallower/drain schedules equal-or-worse
// [R1/R8]; wait POSITION after MFMA clusters is the operative property):
//   stage 2 loads/phase in order A0,A1|A2,A3|B0,B2|B1,B3; s_waitcnt
//   vmcnt(4)@p1 / vmcnt(2)@p3 placed AFTER the MFMA cluster; never drain
//   in-loop. Invariant: entering a tile only B1,B3 of the CURRENT buffer
//   are in flight; first read at p2, retired by p1's vmcnt(4).
// LDS tiles [256][64] bf16, 16B chunk slot XOR-swizzled by (row&7)
// (bank-conflict-free in the GEMM core, measured 0 conflicts).
// ---------------------------------------------------------------------------
template<int DB, int MODE>   // MODE 0 = steady (stage next), 1 = last tile
__device__ __forceinline__ void gemm_tile_cnt(
    const unsigned short* __restrict__ gA, const unsigned short* __restrict__ gB,
    int lda, int ldb, size_t ko,
    unsigned short* lds, char* lA, char* lB,
    const int* aoff, const int* boff, f32x4 acc[4][8])
{
    const char* bA = (const char*)lds + DB * 32768;
    const char* bB = (const char*)lds + 65536 + DB * 32768;
    const int nxt = (DB ^ 1) * 32768;
    short8 av[4][2];
#pragma unroll
    for (int p = 0; p < 4; ++p) {
        if (p == 0) {                            // A-frags once per tile
#pragma unroll
            for (int f = 0; f < 4; f++)
#pragma unroll
                for (int kk = 0; kk < 2; kk++)
                    av[f][kk] = *(const short8*)(bA + (aoff[f] ^ (kk << 6)));
        }
        short8 bv[2][2];
#pragma unroll
        for (int f = 0; f < 2; f++)
#pragma unroll
            for (int kk = 0; kk < 2; kk++)
                bv[f][kk] = *(const short8*)(bB + (boff[p * 2 + f] ^ (kk << 6)));
        if (MODE == 0) {                         // stage next tile, 2 per phase
            if (p == 0) {
                load_lds16(gA + ko,                       lA + nxt);
                load_lds16(gA + ko + (size_t)64 * lda,    lA + nxt + 8192);
            } else if (p == 1) {
                load_lds16(gA + ko + (size_t)128 * lda,   lA + nxt + 16384);
                load_lds16(gA + ko + (size_t)192 * lda,   lA + nxt + 24576);
            } else if (p == 2) {
                load_lds16(gB + ko,                       lB + nxt);
                load_lds16(gB + ko + (size_t)128 * ldb,   lB + nxt + 16384);
            } else {
                load_lds16(gB + ko + (size_t)64 * ldb,    lB + nxt + 8192);
                load_lds16(gB + ko + (size_t)192 * ldb,   lB + nxt + 24576);
            }
        }
        __builtin_amdgcn_s_barrier();
        __builtin_amdgcn_s_setprio(1);
#pragma unroll
        for (int kk = 0; kk < 2; kk++)
#pragma unroll
            for (int f = 0; f < 2; f++)
#pragma unroll
                for (int m = 0; m < 4; m++)
                    acc[m][p * 2 + f] =
                        __builtin_amdgcn_mfma_f32_16x16x32_bf16(
                            av[m][kk], bv[f][kk], acc[m][p * 2 + f], 0, 0, 0);
        __builtin_amdgcn_s_setprio(0);
        if (p == 1) {
            if (MODE == 0) asm volatile("s_waitcnt vmcnt(4)" ::: "memory");
            else           asm volatile("s_waitcnt vmcnt(0)" ::: "memory");
        }
        if (p == 3 && MODE == 0) asm volatile("s_waitcnt vmcnt(2)" ::: "memory");
        if (p < 3 || MODE == 0) __builtin_amdgcn_s_barrier();
    }
}

__device__ __forceinline__ void gemm_core256(
    const unsigned short* __restrict__ A, const unsigned short* __restrict__ B,
    int lda, int ldb, int K,
    unsigned short* lds, f32x4 acc[4][8])
{
    const int t = threadIdx.x;
    const int w = t >> 6, lane = t & 63;
    const int wr = w >> 1, wc = w & 1;          // wave grid 4 (M) x 2 (N)
    const int lm = lane & 15, q = lane >> 4;

    // fragment LDS byte offsets for kk=0; kk=1 is addr ^ 64 (chunk bit2 flip)
    int aoff[4], boff[8];
#pragma unroll
    for (int f = 0; f < 4; f++) {
        const int ra = wr * 64 + f * 16 + lm;
        aoff[f] = ra * 128 + ((q ^ (ra & 7)) << 4);
    }
#pragma unroll
    for (int f = 0; f < 8; f++) {
        const int rb = wc * 128 + f * 16 + lm;
        boff[f] = rb * 128 + ((q ^ (rb & 7)) << 4);
    }

    // staging addresses: load s covers rows [s*64,(s+1)*64); per wave 8 rows
    // x 128 B linear; source chunk pre-swizzled so LDS slot c holds global
    // chunk c ^ (row&7); row&7 == lane>>3 here.
    const int rstep = w * 8 + (lane >> 3);
    const int sc = (lane & 7) ^ (lane >> 3);
    const unsigned short* gA = A + (size_t)rstep * lda + sc * 8;
    const unsigned short* gB = B + (size_t)rstep * ldb + sc * 8;
    char* lA = (char*)lds + w * 1024;            // A buffers: bytes [0,65536)
    char* lB = (char*)lds + 65536 + w * 1024;    // B buffers: bytes [65536,131072)
    const int NT = K >> 6;

    // prologue order A0,A1,A2,A3,B0,B2,B1,B3 matches counted waits:
    // vmcnt(2) leaves B1,B3 in flight (first read at p2, covered by
    // p1's vmcnt(4))
    load_lds16(gA,                       lA);
    load_lds16(gA + (size_t)64 * lda,    lA + 8192);
    load_lds16(gA + (size_t)128 * lda,   lA + 16384);
    load_lds16(gA + (size_t)192 * lda,   lA + 24576);
    load_lds16(gB,                       lB);
    load_lds16(gB + (size_t)128 * ldb,   lB + 16384);
    load_lds16(gB + (size_t)64 * ldb,    lB + 8192);
    load_lds16(gB + (size_t)192 * ldb,   lB + 24576);
    asm volatile("s_waitcnt vmcnt(2)" ::: "memory");
    __builtin_amdgcn_s_barrier();
    int kt = 0;
    for (; kt + 2 < NT; kt += 2) {
        gemm_tile_cnt<0, 0>(gA, gB, lda, ldb, (size_t)(kt + 1) * 64,
                            lds, lA, lB, aoff, boff, acc);
        gemm_tile_cnt<1, 0>(gA, gB, lda, ldb, (size_t)(kt + 2) * 64,
                            lds, lA, lB, aoff, boff, acc);
    }
    gemm_tile_cnt<0, 0>(gA, gB, lda, ldb, (size_t)(NT - 1) * 64,
                        lds, lA, lB, aoff, boff, acc);
    gemm_tile_cnt<1, 1>(gA, gB, lda, ldb, 0, lds, lA, lB, aoff, boff, acc);
    __syncthreads();   // retire all LDS reads before callers reuse LDS
}

// ---------------------------------------------------------------------------
// GEMM1: S = a.b^T * temp; E = mask ? exp(S) : 0. Both E and ET written via
// LDS-transpose coalesced 512B-row stores (direct scattered ET stores cost
// ~20-35 MB write amplification — removed in R9, verified -20 MB WRITE).
// ET-pass swizzle key (jl>>1)&15: R11's jl&15 "fix" left the conflict
// counter EXACTLY unchanged (262144) and drifted attn slower — the counter
// is 2-way aliasing (free per m136), not a cost. Keep R9's verified form.
// Plus atomic l_row / l_col partials.
// Grid: 256 blocks, g = qq*16 + batch -> XCD batch%8 (panel L2 locality).
// ---------------------------------------------------------------------------
__global__ __launch_bounds__(512, 2) void k_gemm_attn(
    const unsigned short* __restrict__ a_bf, const unsigned short* __restrict__ b_bf,
    const int* __restrict__ mask_a, const int* __restrict__ mask_b,
    const float* __restrict__ temp_p,
    unsigned short* __restrict__ E, unsigned short* __restrict__ ET,
    float* __restrict__ l_row, float* __restrict__ l_col)
{
    __shared__ unsigned short lds[65536];        // 128 KiB: staging, E tile, ET tile

    const int g = blockIdx.x;
    const int batch = g & 15;
    const int qq = g >> 4;                       // 0..15
    const int i0 = (qq >> 2) * 256, j0 = (qq & 3) * 256;

    const unsigned short* A = a_bf + (size_t)batch * LA_ * H_ + (size_t)i0 * H_;
    const unsigned short* B = b_bf + (size_t)batch * LB_ * H_ + (size_t)j0 * H_;
    f32x4 acc[4][8];
#pragma unroll
    for (int x = 0; x < 4; x++)
#pragma unroll
        for (int y = 0; y < 8; y++) acc[x][y] = 0;

    gemm_core256(A, B, H_, H_, H_, lds, acc);

    const float temp = temp_p[0];
    const int t = threadIdx.x, w = t >> 6, lane = t & 63;
    const int wr = w >> 1, wc = w & 1, lm = lane & 15, q = lane >> 4;
    const int* map = mask_a + batch * LA_;
    const int* mbp = mask_b + batch * LB_;
    unsigned short* Ep  = E  + (size_t)batch * LA_ * LB_;
    unsigned short* ETp = ET + (size_t)batch * LB_ * LA_;
    float* lrp = l_row + batch * LA_;
    float* lcp = l_col + batch * LB_;

    int mb8[8];
#pragma unroll
    for (int fn = 0; fn < 8; fn++) mb8[fn] = mbp[j0 + wc * 128 + fn * 16 + lm];

    // transform acc -> e in place; write E tile into (now free) LDS with
    // chunk swizzle keyed on (il>>1)&15 (write conflict-free, row-read
    // bijective).
#pragma unroll
    for (int fm = 0; fm < 4; fm++) {
        const int ilb = wr * 64 + fm * 16 + q * 4;
        int ma[4];
#pragma unroll
        for (int r = 0; r < 4; r++) ma[r] = map[i0 + ilb + r];
#pragma unroll
        for (int fn = 0; fn < 8; fn++) {
            const int jl = wc * 128 + fn * 16 + lm;
#pragma unroll
            for (int r = 0; r < 4; r++) {
                const float e = (ma[r] && mb8[fn]) ? __expf(acc[fm][fn][r] * temp) : 0.0f;
                acc[fm][fn][r] = e;
                const int il = ilb + r;
                lds[il * 256 + ((((jl >> 3) ^ ((il >> 1) & 15)) << 3) | (jl & 7))] = f2bf(e);
            }
        }
    }

    // l_row partials: sum over this block's 256 j's (wave holds 128 of them;
    // two waves (wc=0,1) atomically combine)
#pragma unroll
    for (int fm = 0; fm < 4; fm++)
#pragma unroll
        for (int r = 0; r < 4; r++) {
            float s = 0.0f;
#pragma unroll
            for (int fn = 0; fn < 8; fn++) s += acc[fm][fn][r];
            s += __shfl_xor(s, 1, 16); s += __shfl_xor(s, 2, 16);
            s += __shfl_xor(s, 4, 16); s += __shfl_xor(s, 8, 16);
            if (lm == 0) atomicAdd(&lrp[i0 + wr * 64 + fm * 16 + q * 4 + r], s);
        }
    // l_col partials: sum over this block's 256 i's (wave holds 64; four
    // waves (wr) combine)
#pragma unroll
    for (int fn = 0; fn < 8; fn++) {
        float s = 0.0f;
#pragma unroll
        for (int fm = 0; fm < 4; fm++)
#pragma unroll
            for (int r = 0; r < 4; r++) s += acc[fm][fn][r];
        s += __shfl_xor(s, 16, 64); s += __shfl_xor(s, 32, 64);
        if (lane < 16) atomicAdd(&lcp[j0 + wc * 128 + fn * 16 + lm], s);
    }

    // packed E: coalesced 512B-row stores from the swizzled LDS tile
    __syncthreads();
#pragma unroll
    for (int rep = 0; rep < 16; rep++) {
        const int il = (t >> 5) + rep * 16;
        const int c = t & 31;
        const int phys = c ^ ((il >> 1) & 15);
        short8 v = *(const short8*)(lds + il * 256 + phys * 8);
        *(short8*)(Ep + (size_t)(i0 + il) * LB_ + j0 + c * 8) = v;
    }

    // ET tile: overwrite LDS with the transposed layout (rows = jl, 256
    // ushorts of il), chunk swizzle keyed on (jl>>1)&15 (mirror of E pass),
    // then stream ET as coalesced 512B rows.
    __syncthreads();
#pragma unroll
    for (int fm = 0; fm < 4; fm++) {
        const int ilb = wr * 64 + fm * 16 + q * 4;
        const int chunk = ilb >> 3, sub = ilb & 7;
#pragma unroll
        for (int fn = 0; fn < 8; fn++) {
            const int jl = wc * 128 + fn * 16 + lm;
            ushort4 pk;
            unsigned short* pp = (unsigned short*)&pk;
#pragma unroll
            for (int r = 0; r < 4; r++) pp[r] = f2bf(acc[fm][fn][r]);
            *(ushort4*)(lds + jl * 256 + (((chunk ^ ((jl >> 1) & 15)) << 3) | sub)) = pk;
        }
    }
    __syncthreads();
#pragma unroll
    for (int rep = 0; rep < 16; rep++) {
        const int jl = (t >> 5) + rep * 16;
        const int c = t & 31;
        const int phys = c ^ ((jl >> 1) & 15);
        short8 v = *(const short8*)(lds + jl * 256 + phys * 8);
        *(short8*)(ETp + (size_t)(j0 + jl) * LA_ + i0 + c * 8) = v;
    }
}

// ---------------------------------------------------------------------------
// GEMM2+3 merged: zc<16 -> feature_a (E . bT^T), zc>=16 -> feature_b (ET.aT^T)
// Grid: 256 blocks, g = qq*32 + zc -> XCD zc%8 (A-tile/B-panel L2 sharing).
// ---------------------------------------------------------------------------
__global__ __launch_bounds__(512, 2) void k_gemm_feat(
    const unsigned short* __restrict__ E, const unsigned short* __restrict__ ET,
    const unsigned short* __restrict__ aT, const unsigned short* __restrict__ bT,
    const int* __restrict__ mask_a, const int* __restrict__ mask_b,
    const int* __restrict__ nA, const int* __restrict__ nB,
    const float* __restrict__ l_row, const float* __restrict__ l_col,
    const float* __restrict__ mean_a, const float* __restrict__ mean_b,
    float* __restrict__ out)
{
    __shared__ unsigned short lds[65536];

    const int g = blockIdx.x;
    const int zc = g & 31;
    const int qq = g >> 5;                       // 0..7
    const int n0 = (qq & 1) * 256, m0 = (qq >> 1) * 256;

    const int batch = zc & 15;
    const bool isA = zc < 16;
    const unsigned short* Amat = (isA ? E : ET) + (size_t)batch * 1024 * 1024;
    const unsigned short* Bm   = (isA ? bT : aT) + (size_t)batch * H_ * 1024;
    const int* mp   = (isA ? mask_a : mask_b) + batch * 1024;
    const int nn    = (isA ? nB : nA)[batch];
    const float* sp = (isA ? l_row : l_col) + batch * 1024;
    const float* mv = (isA ? mean_b : mean_a) + batch * H_;
    float* op = out + (isA ? (size_t)0 : (size_t)NB_ * LA_ * H_) + (size_t)batch * 1024 * H_;

    f32x4 acc[4][8];
#pragma unroll
    for (int x = 0; x < 4; x++)
#pragma unroll
        for (int y = 0; y < 8; y++) acc[x][y] = 0;

    gemm_core256(Amat + (size_t)m0 * 1024, Bm + (size_t)n0 * 1024,
                 1024, 1024, 1024, lds, acc);

    const int t = threadIdx.x, w = t >> 6, lane = t & 63;
    const int wr = w >> 1, wc = w & 1, lm = lane & 15, q = lane >> 4;

    float mval[8];
#pragma unroll
    for (int fn = 0; fn < 8; fn++) mval[fn] = mv[n0 + wc * 128 + fn * 16 + lm];

#pragma unroll
    for (int fm = 0; fm < 4; fm++) {
        const int ib = m0 + wr * 64 + fm * 16 + q * 4;
#pragma unroll
        for (int r = 0; r < 4; r++) {
            const int i = ib + r;
            const bool valid = (mp[i] != 0) && (nn > 0);
            const float inv = valid ? 1.0f / sp[i] : 0.0f;
#pragma unroll
            for (int fn = 0; fn < 8; fn++) {
                const int d = n0 + wc * 128 + fn * 16 + lm;
                op[(size_t)i * H_ + d] = valid ? acc[fm][fn][r] * inv : mval[fn];
            }
        }
    }
}

// ---------------------------------------------------------------------------
// prep: block-owned column panels -> NO atomics.  [R6 version; 2x and 4x
// parallelism splits both measured null-to-negative (R7, R11) — this kernel
// is barrier/latency-floor-bound, not occupancy-bound]
// Blocks 0..255: (sel, batch, 64-d strip); loop over all 1024 tokens:
//   fp32 -> bf16 row-major + LDS-transposed bf16, column sums in registers,
//   shfl + small-LDS reduce -> direct mean store (single writer).
// Blocks 256..287: zero l_row/l_col (128 KB) + per-batch mask counts.
// ---------------------------------------------------------------------------
__global__ __launch_bounds__(256) void k_prep(
    const float* __restrict__ a, const float* __restrict__ b,
    unsigned short* __restrict__ aN, unsigned short* __restrict__ bN,
    unsigned short* __restrict__ aT, unsigned short* __restrict__ bT,
    float* __restrict__ mean_a, float* __restrict__ mean_b,
    const int* __restrict__ mask_a, const int* __restrict__ mask_b,
    int* __restrict__ nA, int* __restrict__ nB,
    float* __restrict__ zero_base)
{
    const int g = blockIdx.x, t = threadIdx.x;
    if (g >= 256) {
        const int s = g - 256;                   // 0..31
        *(float4*)(zero_base + ((size_t)s * 256 + t) * 4) = make_float4(0, 0, 0, 0);
        const int batch = s & 15, which = s >> 4;
        const int* m = (which ? mask_b : mask_a) + batch * 1024;
        int cnt = m[t] + m[t + 256] + m[t + 512] + m[t + 768];
        __shared__ int red[256];
        red[t] = cnt;
        __syncthreads();
        for (int off = 128; off; off >>= 1) {
            if (t < off) red[t] += red[t + off];
            __syncthreads();
        }
        if (t == 0) (which ? nB : nA)[batch] = red[0];
        return;
    }
    const int dstrip = g & 7, batch = (g >> 3) & 15, sel = g >> 7;
    const float* src = (sel ? b : a) + (size_t)batch * 1024 * H_;
    unsigned short* np = (sel ? bN : aN) + (size_t)batch * 1024 * H_;
    unsigned short* tp = (sel ? bT : aT) + (size_t)batch * H_ * 1024;
    float* mdst = (sel ? mean_b : mean_a) + batch * H_;
    const int d0 = dstrip * 64;

    __shared__ unsigned short lds[64][68];
    __shared__ float cs[4][64];
    const int c4 = (t & 15) * 4;
    float colsum[4] = {0.f, 0.f, 0.f, 0.f};
    for (int i0 = 0; i0 < 1024; i0 += 64) {
#pragma unroll
        for (int it = 0; it < 4; it++) {
            const int r = (t >> 4) + it * 16;
            float4 v = *(const float4*)(src + (size_t)(i0 + r) * H_ + d0 + c4);
            colsum[0] += v.x; colsum[1] += v.y; colsum[2] += v.z; colsum[3] += v.w;
            ushort4 u = make_ushort4(f2bf(v.x), f2bf(v.y), f2bf(v.z), f2bf(v.w));
            *(ushort4*)(np + (size_t)(i0 + r) * H_ + d0 + c4) = u;
            *(ushort4*)&lds[r][c4] = u;
        }
        __syncthreads();
#pragma unroll
        for (int it = 0; it < 4; it++) {
            const int dd = (t >> 4) + it * 16;
            const int i4 = (t & 15) * 4;
            ushort4 u = make_ushort4(lds[i4][dd], lds[i4 + 1][dd],
                                     lds[i4 + 2][dd], lds[i4 + 3][dd]);
            *(ushort4*)(tp + (size_t)(d0 + dd) * 1024 + i0 + i4) = u;
        }
        __syncthreads();
    }
    // columns are shared by threads t, t^16, t^32 (within wave) x 4 waves
#pragma unroll
    for (int j = 0; j < 4; j++) {
        colsum[j] += __shfl_xor(colsum[j], 16, 64);
        colsum[j] += __shfl_xor(colsum[j], 32, 64);
    }
    const int w = t >> 6, lane = t & 63;
    if (lane < 16) {
#pragma unroll
        for (int j = 0; j < 4; j++) cs[w][c4 + j] = colsum[j];
    }
    __syncthreads();
    if (t < 64) mdst[d0 + t] = (cs[0][t] + cs[1][t] + cs[2][t] + cs[3][t]) * (1.0f / 1024.0f);
}

// ---------------------------------------------------------------------------
extern "C" void kernel_launch(void* const* d_in, const int* in_sizes, int n_in,
                              void* d_out, int out_size, void* d_ws, size_t ws_size,
                              hipStream_t stream)
{
    const float* a      = (const float*)d_in[0];
    const float* b      = (const float*)d_in[1];
    const int*   mask_a = (const int*)d_in[2];
    const int*   mask_b = (const int*)d_in[3];
    const float* temp   = (const float*)d_in[4];
    float* out = (float*)d_out;

    // workspace layout (~128.2 MiB)
    char* ws = (char*)d_ws;
    size_t off = 0;
    unsigned short* E    = (unsigned short*)(ws + off); off += (size_t)NB_ * LA_ * LB_ * 2;  // 32 MiB
    unsigned short* ET   = (unsigned short*)(ws + off); off += (size_t)NB_ * LB_ * LA_ * 2;  // 32 MiB
    unsigned short* a_bf = (unsigned short*)(ws + off); off += (size_t)NB_ * LA_ * H_ * 2;   // 16 MiB
    unsigned short* b_bf = (unsigned short*)(ws + off); off += (size_t)NB_ * LB_ * H_ * 2;   // 16 MiB
    unsigned short* aT   = (unsigned short*)(ws + off); off += (size_t)NB_ * H_ * LA_ * 2;   // 16 MiB
    unsigned short* bT   = (unsigned short*)(ws + off); off += (size_t)NB_ * H_ * LB_ * 2;   // 16 MiB
    float* l_row  = (float*)(ws + off); off += (size_t)NB_ * LA_ * 4;   // zeroed region start
    float* l_col  = (float*)(ws + off); off += (size_t)NB_ * LB_ * 4;
    float* mean_a = (float*)(ws + off); off += (size_t)NB_ * H_ * 4;
    float* mean_b = (float*)(ws + off); off += (size_t)NB_ * H_ * 4;
    int*   nA     = (int*)(ws + off); off += 64;
    int*   nB     = (int*)(ws + off); off += 64;

    // prep (also zeroes l_row/l_col and computes mask counts)
    k_prep<<<dim3(288), 256, 0, stream>>>(
        a, b, a_bf, b_bf, aT, bT, mean_a, mean_b,
        mask_a, mask_b, nA, nB, l_row);

    k_gemm_attn<<<dim3(256), 512, 0, stream>>>(
        a_bf, b_bf, mask_a, mask_b, temp, E, ET, l_row, l_col);

    k_gemm_feat<<<dim3(256), 512, 0, stream>>>(
        E, ET, aT, bT, mask_a, mask_b, nA, nB, l_row, l_col, mean_a, mean_b, out);
}